// Round 3
// baseline (3778.652 us; speedup 1.0000x reference)
//
#include <hip/hip_runtime.h>
#include <hip/hip_bf16.h>
#include <math.h>

// Problem dims (fixed)
#define TT   64
#define BBATCH 64
#define NTOK 64
#define DDIM 128
#define HIDN 256
#define BN   4096     // BBATCH*NTOK

typedef short bf16x8 __attribute__((ext_vector_type(8)));
typedef float f32x4  __attribute__((ext_vector_type(4)));

// ---------------------------------------------------------------------------
// G = C_low^T C_low : symmetric 64x64 Gram of the first 16 orthonormal DCT-II
// rows. lowpass_time(x) == G @ x along time.
// ---------------------------------------------------------------------------
__global__ void k_gram(float* __restrict__ G) {
  int s = blockIdx.x, t = threadIdx.x;
  double acc = 0.0;
  for (int k = 0; k < 16; ++k) {
    double ct, cs;
    if (k == 0) { ct = 0.125; cs = 0.125; }  // sqrt(1/64)
    else {
      const double f = 0.17677669529663687;  // sqrt(2/64)
      ct = cos(M_PI * (t + 0.5) * k / 64.0) * f;
      cs = cos(M_PI * (s + 0.5) * k / 64.0) * f;
    }
    acc += ct * cs;
  }
  G[s * 64 + t] = (float)acc;
}

// ---------------------------------------------------------------------------
// k_lowpass: unchanged from R2 (worked: ~90 us, bit-exact M/G pipeline).
// ---------------------------------------------------------------------------
__global__ __launch_bounds__(256) void k_lowpass(
    const float* __restrict__ x, const float* __restrict__ mx,
    const float* __restrict__ G, float* __restrict__ xlp) {
  __shared__ float Gl[64 * 68];
  __shared__ float Ml[64 * 128];
  const int bn = blockIdx.x;
  const int b = bn >> 6, n = bn & 63;
#pragma unroll
  for (int i = 0; i < 4; ++i) {
    int idx4 = threadIdx.x + i * 256;
    int s = idx4 >> 4, tq = (idx4 & 15) * 4;
    *(float4*)&Gl[s * 68 + tq] = *(const float4*)&G[s * 64 + tq];
  }
  const float* mxs = mx + (size_t)(n * 64 + b) * 8192;
#pragma unroll
  for (int i = 0; i < 8; ++i) {
    int idx4 = threadIdx.x + i * 256;
    int s = idx4 >> 5, dq = (idx4 & 31) * 4;
    const float4 xv = *(const float4*)&x[(size_t)(s * 4096 + bn) * 128 + dq];
    const float4 mv = *(const float4*)&mxs[idx4 * 4];
    float4 r;
    {
#pragma clang fp contract(off)
      r.x = xv.x * (0.05f * mv.x + 0.95f * mv.x);
      r.y = xv.y * (0.05f * mv.y + 0.95f * mv.y);
      r.z = xv.z * (0.05f * mv.z + 0.95f * mv.z);
      r.w = xv.w * (0.05f * mv.w + 0.95f * mv.w);
    }
    *(float4*)&Ml[s * 128 + dq] = r;
  }
  __syncthreads();
  const int mq = threadIdx.x >> 4;
  const int ng = threadIdx.x & 15;
  float accA[4][8], accB[4][8];
#pragma unroll
  for (int i = 0; i < 4; ++i)
#pragma unroll
    for (int j = 0; j < 8; ++j) { accA[i][j] = 0.f; accB[i][j] = 0.f; }
#pragma unroll 8
  for (int s = 0; s < 32; ++s) {
    float av[4]; *(float4*)av = *(const float4*)&Gl[s * 68 + mq * 4];
    float bv[8];
    *(float4*)&bv[0] = *(const float4*)&Ml[s * 128 + ng * 8];
    *(float4*)&bv[4] = *(const float4*)&Ml[s * 128 + ng * 8 + 4];
#pragma unroll
    for (int i = 0; i < 4; ++i)
#pragma unroll
      for (int j = 0; j < 8; ++j) accA[i][j] = fmaf(av[i], bv[j], accA[i][j]);
  }
#pragma unroll 8
  for (int s = 32; s < 64; ++s) {
    float av[4]; *(float4*)av = *(const float4*)&Gl[s * 68 + mq * 4];
    float bv[8];
    *(float4*)&bv[0] = *(const float4*)&Ml[s * 128 + ng * 8];
    *(float4*)&bv[4] = *(const float4*)&Ml[s * 128 + ng * 8 + 4];
#pragma unroll
    for (int i = 0; i < 4; ++i)
#pragma unroll
      for (int j = 0; j < 8; ++j) accB[i][j] = fmaf(av[i], bv[j], accB[i][j]);
  }
#pragma unroll
  for (int i = 0; i < 4; ++i) {
    int t = mq * 4 + i;
    float4 o0, o1;
    o0.x = accA[i][0] + accB[i][0]; o0.y = accA[i][1] + accB[i][1];
    o0.z = accA[i][2] + accB[i][2]; o0.w = accA[i][3] + accB[i][3];
    o1.x = accA[i][4] + accB[i][4]; o1.y = accA[i][5] + accB[i][5];
    o1.z = accA[i][6] + accB[i][6]; o1.w = accA[i][7] + accB[i][7];
    size_t base = (size_t)(t * 4096 + bn) * 128 + ng * 8;
    *(float4*)&xlp[base] = o0;
    *(float4*)&xlp[base + 4] = o1;
  }
}

// ---------------------------------------------------------------------------
// Row-scan GEMM + LIF, zero LDS / zero barriers.
//   lane  = output column c (blockIdx.y*128 + tid), weight column W[:,c]
//           preloaded into VGPRs (static-indexed, fully unrolled).
//   A row = wave-uniform values -> scalar loads, free SGPR operands in v_fma.
//   t-loop is the LIF scan itself; v lives in a register; no epilogue.
// ASPIKE: A holds bf16 spike bits (0/0x3F80) -> uniform 1-scalar-op unpack.
// OMODE 0: store bf16 spike bits (stride NW). OMODE 1: out = gate*(1-spike).
// 4 interleaved accumulators hide the 4-cyc FMA latency; summation order
// differs from R1 only by fp32-reorder-level noise (proven spike-safe).
// ---------------------------------------------------------------------------
template <int K, int NW, bool ASPIKE, int OMODE>
__global__ __launch_bounds__(128) void k_gemm_lif_rs(
    const void* __restrict__ Ap, const float* __restrict__ W,
    const float* __restrict__ gate, void* __restrict__ outp) {
  const int bn = blockIdx.x;
  const int c = blockIdx.y * 128 + threadIdx.x;
  float wreg[K];
#pragma unroll
  for (int k = 0; k < K; ++k) wreg[k] = W[(size_t)k * NW + c];

  float v = 0.f;
  for (int t = 0; t < 64; ++t) {
    const size_t row = (size_t)(t * 4096 + bn);
    float a0 = 0.f, a1 = 0.f, a2 = 0.f, a3 = 0.f;
    if (ASPIKE) {
      const unsigned int* Ar = (const unsigned int*)Ap + row * (K / 2);
#pragma unroll
      for (int k2 = 0; k2 < K / 2; k2 += 2) {
        unsigned int d0 = Ar[k2], d1 = Ar[k2 + 1];
        a0 = fmaf(__uint_as_float(d0 << 16),          wreg[2 * k2 + 0], a0);
        a1 = fmaf(__uint_as_float(d0 & 0xFFFF0000u), wreg[2 * k2 + 1], a1);
        a2 = fmaf(__uint_as_float(d1 << 16),          wreg[2 * k2 + 2], a2);
        a3 = fmaf(__uint_as_float(d1 & 0xFFFF0000u), wreg[2 * k2 + 3], a3);
      }
    } else {
      const float* Ar = (const float*)Ap + row * K;
#pragma unroll
      for (int k = 0; k < K; k += 4) {
        a0 = fmaf(Ar[k + 0], wreg[k + 0], a0);
        a1 = fmaf(Ar[k + 1], wreg[k + 1], a1);
        a2 = fmaf(Ar[k + 2], wreg[k + 2], a2);
        a3 = fmaf(Ar[k + 3], wreg[k + 3], a3);
      }
    }
    float pre = (a0 + a1) + (a2 + a3);
    {
#pragma clang fp contract(off)
      float dlt = (pre - v) * 0.5f;  // v + (pre - v)/tau, tau = 2
      v = v + dlt;
    }
    bool s = (v >= 1.0f);
    if (OMODE == 0) {
      ((unsigned short*)outp)[row * NW + c] =
          s ? (unsigned short)0x3F80 : (unsigned short)0;
    } else {
      float g = gate[row * 128 + c];
      ((float*)outp)[row * 128 + c] = s ? 0.f : g;  // g*(1-s) exact
    }
    v = s ? 0.f : v;  // detached hard reset
  }
}

// ---------------------------------------------------------------------------
// Spiking 2-head attention per (t,b):  S = q k^T * 0.125 ; O = S v.
// Exact in bf16 MFMA (spikes in {0,1}; S integer<=64; O multiples of 1/8).
// ---------------------------------------------------------------------------
__global__ __launch_bounds__(256) void k_attn(
    const unsigned short* __restrict__ q, const unsigned short* __restrict__ kk,
    const unsigned short* __restrict__ vv, float* __restrict__ o) {
  __shared__ unsigned short ql[64 * 136];
  __shared__ unsigned short kl[64 * 136];
  __shared__ unsigned short vt[128 * 72];
  __shared__ unsigned short sl[64 * 72];
  const size_t base = (size_t)blockIdx.x * 8192;
#pragma unroll
  for (int i = 0; i < 4; ++i) {
    int idx8 = threadIdx.x + i * 256;
    int n = idx8 >> 4, d8 = (idx8 & 15) * 8;
    uint4 pq = *(const uint4*)&q[base + n * 128 + d8];
    uint4 pk = *(const uint4*)&kk[base + n * 128 + d8];
    *(uint4*)&ql[n * 136 + d8] = pq;
    *(uint4*)&kl[n * 136 + d8] = pk;
    uint4 pv = *(const uint4*)&vv[base + n * 128 + d8];
    unsigned short e[8] = {
        (unsigned short)(pv.x & 0xFFFF), (unsigned short)(pv.x >> 16),
        (unsigned short)(pv.y & 0xFFFF), (unsigned short)(pv.y >> 16),
        (unsigned short)(pv.z & 0xFFFF), (unsigned short)(pv.z >> 16),
        (unsigned short)(pv.w & 0xFFFF), (unsigned short)(pv.w >> 16)};
#pragma unroll
    for (int j = 0; j < 8; ++j) vt[(d8 + j) * 72 + n] = e[j];
  }
  __syncthreads();
  const int lane = threadIdx.x & 63;
  const int w = threadIdx.x >> 6;
  const int l15 = lane & 15, l4 = lane >> 4;
  for (int h = 0; h < 2; ++h) {
    bf16x8 af0 = *(const bf16x8*)&ql[(w * 16 + l15) * 136 + h * 64 + l4 * 8];
    bf16x8 af1 = *(const bf16x8*)&ql[(w * 16 + l15) * 136 + h * 64 + 32 + l4 * 8];
#pragma unroll
    for (int tj = 0; tj < 4; ++tj) {
      f32x4 cc = {0.f, 0.f, 0.f, 0.f};
      bf16x8 b0 = *(const bf16x8*)&kl[(tj * 16 + l15) * 136 + h * 64 + l4 * 8];
      cc = __builtin_amdgcn_mfma_f32_16x16x32_bf16(af0, b0, cc, 0, 0, 0);
      bf16x8 b1 = *(const bf16x8*)&kl[(tj * 16 + l15) * 136 + h * 64 + 32 + l4 * 8];
      cc = __builtin_amdgcn_mfma_f32_16x16x32_bf16(af1, b1, cc, 0, 0, 0);
#pragma unroll
      for (int r = 0; r < 4; ++r) {
        float sp = cc[r] * 0.125f;  // exact
        sl[(w * 16 + l4 * 4 + r) * 72 + tj * 16 + l15] =
            (unsigned short)(__float_as_uint(sp) >> 16);
      }
    }
    __syncthreads();
    bf16x8 a20 = *(const bf16x8*)&sl[(w * 16 + l15) * 72 + l4 * 8];
    bf16x8 a21 = *(const bf16x8*)&sl[(w * 16 + l15) * 72 + 32 + l4 * 8];
#pragma unroll
    for (int tj = 0; tj < 4; ++tj) {
      f32x4 cc = {0.f, 0.f, 0.f, 0.f};
      bf16x8 b0 = *(const bf16x8*)&vt[(h * 64 + tj * 16 + l15) * 72 + l4 * 8];
      cc = __builtin_amdgcn_mfma_f32_16x16x32_bf16(a20, b0, cc, 0, 0, 0);
      bf16x8 b1 = *(const bf16x8*)&vt[(h * 64 + tj * 16 + l15) * 72 + 32 + l4 * 8];
      cc = __builtin_amdgcn_mfma_f32_16x16x32_bf16(a21, b1, cc, 0, 0, 0);
#pragma unroll
      for (int r = 0; r < 4; ++r)
        o[base + (size_t)(w * 16 + l4 * 4 + r) * 128 + h * 64 + tj * 16 + l15] = cc[r];
    }
    __syncthreads();
  }
}

// ---------------------------------------------------------------------------
extern "C" void kernel_launch(void* const* d_in, const int* in_sizes, int n_in,
                              void* d_out, int out_size, void* d_ws, size_t ws_size,
                              hipStream_t stream) {
  const float* x  = (const float*)d_in[0];
  const float* mx = (const float*)d_in[1];
  const float* Wq = (const float*)d_in[2];
  const float* Wk = (const float*)d_in[3];
  const float* Wv = (const float*)d_in[4];
  const float* Wo = (const float*)d_in[5];
  const float* W1 = (const float*)d_in[6];
  const float* W2 = (const float*)d_in[7];
  float* out = (float*)d_out;

  char* w = (char*)d_ws;
  float* G   = (float*)w;                                   // 16 KB (pad 64K)
  float* xlp = (float*)(w + 65536);                         // 134 MB, later o
  float* x2  = (float*)(w + 65536 + 134217728ull);          // 134 MB
  unsigned short* sq = (unsigned short*)(w + 65536 + 268435456ull);  // 67 MB
  unsigned short* sk = sq + 33554432ull;                    // 67 MB
  unsigned short* sv = sk + 33554432ull;                    // 67 MB
  unsigned short* sh = sq;  // mlp hidden spikes (bf16 bits) overlay sq+sk

  k_gram<<<64, 64, 0, stream>>>(G);
  k_lowpass<<<4096, 256, 0, stream>>>(x, mx, G, xlp);
  // q from x; k,v from lowpassed memory stream
  k_gemm_lif_rs<128, 128, false, 0><<<dim3(4096, 1), 128, 0, stream>>>(x,   Wq, nullptr, sq);
  k_gemm_lif_rs<128, 128, false, 0><<<dim3(4096, 1), 128, 0, stream>>>(xlp, Wk, nullptr, sk);
  k_gemm_lif_rs<128, 128, false, 0><<<dim3(4096, 1), 128, 0, stream>>>(xlp, Wv, nullptr, sv);
  k_attn<<<4096, 256, 0, stream>>>(sq, sk, sv, xlp);  // o overwrites xlp
  // attn_spk = lif(o @ Wo); x2 = x * (1 - attn_spk)
  k_gemm_lif_rs<128, 128, false, 1><<<dim3(4096, 1), 128, 0, stream>>>(xlp, Wo, x, x2);
  // mlp: sh = lif(x2 @ W1) as bf16 spike bits (256-wide); out = x2*(1-lif(sh@W2))
  k_gemm_lif_rs<128, 256, false, 0><<<dim3(4096, 2), 128, 0, stream>>>(x2, W1, nullptr, sh);
  k_gemm_lif_rs<256, 128, true,  1><<<dim3(4096, 1), 128, 0, stream>>>(sh, W2, x2, out);
}